// Round 17
// baseline (21.078 us; speedup 1.0000x reference)
//
#include <hip/hip_runtime.h>
#include <math.h>

// DMLoss fused kernel for MI355X (gfx950).
// Round 17: dual-chain packed scans. R16 ruled out DS throughput (cut 1/3 of
// scan bytes -> -0.2us); remaining model = VALU issue count. Pack TWO
// independent rolling-D chains (segs [m0,m0+16) and [m0+16,m0+32)) into v2f
// via inline-asm v_pk_{add,mul,fma}_f32 (R4-proven); med3/rint/cmp/cndmask
// stay scalar. Phase C packs candidate PAIRS via float4 s_ii reads. Exact
// first-occurrence ties: chain0 indices < chain1 indices -> strict < merge.
// Everything else byte-identical to R16 (best, 17.9us).

#define BB 1024
#define NN 128
#define MM 128

typedef float v2f __attribute__((ext_vector_type(2)));

__device__ __forceinline__ v2f pk_add(v2f a, v2f b) {
    v2f d; asm("v_pk_add_f32 %0, %1, %2" : "=v"(d) : "v"(a), "v"(b)); return d;
}
__device__ __forceinline__ v2f pk_mul(v2f a, v2f b) {
    v2f d; asm("v_pk_mul_f32 %0, %1, %2" : "=v"(d) : "v"(a), "v"(b)); return d;
}
__device__ __forceinline__ v2f pk_fma(v2f a, v2f b, v2f c) {
    v2f d; asm("v_pk_fma_f32 %0, %1, %2, %3" : "=v"(d) : "v"(a), "v"(b), "v"(c)); return d;
}

__device__ __forceinline__ float sl1(float x) {
    float d = fabsf(x);
    return d < 1.0f ? 0.5f * d * d : d - 0.5f;
}

__global__ void __launch_bounds__(256, 8)
dmloss_main(const float* __restrict__ ini, const float* __restrict__ pred,
            const float* __restrict__ gt,  const float* __restrict__ kmask,
            float4* __restrict__ partials)
{
    const int b    = blockIdx.x >> 1;
    const int half = blockIdx.x & 1;      // owns points [64*half, 64*half+64)
    const int tid  = threadIdx.x;
    const int g    = tid & 63;            // owned point: P = 64*half + g
    const int h    = tid >> 6;            // 0..3: scan slice (32 segs / 32 ini)
    const int P    = (half << 6) + g;

    __shared__ __align__(16) float2 s_gt[MM];
    __shared__ __align__(16) float2 s_pr[NN];
    __shared__ __align__(16) float2 s_ii[NN];
    __shared__ float4 s_seg[MM];                 // (gx, gy, 5/|e|^2, |e|^2/100)
    __shared__ float  s_step[16];                // exact j/10
    __shared__ float  s_rv[4 * 64];
    __shared__ float  s_rf[4 * 64];
    __shared__ float  s_sum[3][4];

    const float2* gt2 = (const float2*)(gt   + (size_t)b * MM * 2);
    const float2* in2 = (const float2*)(ini  + (size_t)b * NN * 2);
    const float2* pr2 = (const float2*)(pred + (size_t)b * NN * 2);

    // ---- staging (one barrier): 256 threads cover 128 segs + 128 pr/ii ----
    if (tid < 128) {
        int m = tid;
        float2 gm = gt2[m];
        s_gt[m] = gm;
        float2 a  = gt2[(m + 127) & 127];
        float ex = gm.x - a.x, ey = gm.y - a.y;
        float A  = ex * ex + ey * ey;
        float inv5 = A > 0.f ? 5.f / A : 0.f;   // degenerate: jv=5, E=0 -> d=Da
        s_seg[m] = make_float4(gm.x, gm.y, inv5, A * 0.01f);
        if (tid < 16) s_step[tid] = (float)tid / 10.0f;
    } else {
        int k = tid - 128;
        s_pr[k] = pr2[k];
        s_ii[k] = in2[k];
    }
    float2 myP  = in2[P];                  // ini_pred point (Phase B owner)
    float2 myG  = gt2[P];                  // gt point (Phase C owner)
    const float px = myP.x, py = myP.y;
    __syncthreads();

    float sumA = 0.f, sumB = 0.f, sumC = 0.f;

    // ---- Phase B: two packed rolling-D chains over [m0,m0+16), [m0+16,m0+32) ----
    // Dg = dist^2(p, gt[m]); jv = (Da-Dg)*inv5 + 5; jr = rint(med3(jv,0,9));
    // d = Da + (E*jr)*(jr - 2*jv); fi = 10*m + jr. Chain arithmetic identical
    // to R16 (bit-exact), incl. chain1's fresh Da init (same coords + fma order).
    float b0, f0;
    {
        const int m0 = 32 * h;
        const v2f pxn = { -px, -px };
        const v2f pyn = { -py, -py };
        const v2f M1  = { -1.f, -1.f };
        const v2f M2  = { -2.f, -2.f };
        const v2f F5  = { 5.f, 5.f };
        float2 a0 = s_gt[(m0 + 127) & 127];
        float2 a1 = s_gt[m0 + 15];
        float dax0 = a0.x - px, day0 = a0.y - py;
        float dax1 = a1.x - px, day1 = a1.y - py;
        v2f Da = { fmaf(day0, day0, dax0 * dax0),
                   fmaf(day1, day1, dax1 * dax1) };
        float dB0 = INFINITY, dB1 = INFINITY;
        float fB0 = 1e30f, fB1 = 1e30f;
        float fm = (float)(320 * h);     // chain0 base; chain1 = fm + 160
        #pragma unroll 4
        for (int j = 0; j < 16; ++j) {
            float4 S0 = s_seg[m0 + j];
            float4 S1 = s_seg[m0 + 16 + j];
            v2f gx = { S0.x, S1.x }, gy = { S0.y, S1.y };
            v2f i5 = { S0.z, S1.z }, E  = { S0.w, S1.w };
            v2f dgx = pk_add(gx, pxn);               // gt - p
            v2f dgy = pk_add(gy, pyn);
            v2f Dg  = pk_fma(dgy, dgy, pk_mul(dgx, dgx));
            v2f dd  = pk_fma(Dg, M1, Da);            // Da - Dg
            v2f jv  = pk_fma(dd, i5, F5);
            float jr0 = rintf(__builtin_amdgcn_fmed3f(jv.x, 0.f, 9.f));
            float jr1 = rintf(__builtin_amdgcn_fmed3f(jv.y, 0.f, 9.f));
            v2f jr  = { jr0, jr1 };
            v2f t   = pk_fma(jv, M2, jr);            // jr - 2*jv
            v2f d   = pk_fma(pk_mul(E, jr), t, Da);
            float fi0 = fm + jr0;
            float fi1 = (fm + 160.f) + jr1;
            if (d.x < dB0) { dB0 = d.x; fB0 = fi0; } // ascending per chain
            if (d.y < dB1) { dB1 = d.y; fB1 = fi1; }
            Da = Dg;
            fm += 10.f;
        }
        // chain0 indices < chain1 indices -> tie keeps chain0 (strict <)
        b0 = dB0; f0 = fB0;
        if (dB1 < dB0) { b0 = dB1; f0 = fB1; }
    }
    s_rv[h * 64 + g] = b0;
    s_rf[h * 64 + g] = f0;
    __syncthreads();

    // merge 4 slices (64 active threads) + exact epilogue A
    if (tid < 64) {
        float best = s_rv[tid], bf = s_rf[tid];
        #pragma unroll
        for (int q = 1; q < 4; ++q) {
            float ov = s_rv[q * 64 + tid];
            float of = s_rf[q * 64 + tid];
            if (ov < best || (ov == best && of < bf)) { best = ov; bf = of; }
        }
        int bidx = (int)bf;
        int m = bidx / 10;
        int j = bidx - m * 10;
        float s  = s_step[j];
        float tt = 1.0f - s;
        float2 gm = s_gt[m];
        float2 gp = s_gt[(m + 127) & 127];
        float gx = gm.x * s + gp.x * tt;   // exact reference interp formula
        float gy = gm.y * s + gp.y * tt;
        float2 pr = s_pr[(half << 6) + tid];
        sumA = sl1(pr.x - gx) + sl1(pr.y - gy);
    }
    __syncthreads();   // protect s_rv/s_rf reuse

    // ---- Phase C: owned gt point vs ini slice [32h, 32h+32), pair-packed ----
    {
        const float gx = myG.x, gy = myG.y;
        const v2f gxn = { -gx, -gx };
        const v2f gyn = { -gy, -gy };
        float b1 = INFINITY, f1 = 1e30f;
        float fk = (float)(32 * h);
        const int k0 = 32 * h;
        #pragma unroll 4
        for (int j = 0; j < 16; ++j) {
            float4 I = *(const float4*)(&s_ii[k0 + 2 * j]);   // 2 ini points
            v2f dx = pk_add((v2f){ I.x, I.z }, gxn);
            v2f dy = pk_add((v2f){ I.y, I.w }, gyn);
            v2f d  = pk_fma(dy, dy, pk_mul(dx, dx));
            if (d.x < b1) { b1 = d.x; f1 = fk; }         // index 2j
            if (d.y < b1) { b1 = d.y; f1 = fk + 1.f; }   // index 2j+1 (tie keeps x)
            fk += 2.f;
        }
        s_rv[h * 64 + g] = b1;
        s_rf[h * 64 + g] = f1;
    }
    __syncthreads();

    if (tid < 64) {
        float best = s_rv[tid], bf = s_rf[tid];
        #pragma unroll
        for (int q = 1; q < 4; ++q) {
            float ov = s_rv[q * 64 + tid];
            float of = s_rf[q * 64 + tid];
            if (ov < best || (ov == best && of < bf)) { best = ov; bf = of; }
        }
        int k = (int)bf;
        float2 pk2 = s_pr[k];
        float2 g0  = s_gt[(half << 6) + tid];
        float  km  = kmask[b * MM + (half << 6) + tid];
        sumB = km * (sl1(pk2.x - g0.x) + sl1(pk2.y - g0.y));
        sumC = km;
    }

    // ---- Block reduction ----
    #pragma unroll
    for (int off = 32; off > 0; off >>= 1) {
        sumA += __shfl_down(sumA, off);
        sumB += __shfl_down(sumB, off);
        sumC += __shfl_down(sumC, off);
    }
    const int wave = tid >> 6;
    if ((tid & 63) == 0) {
        s_sum[0][wave] = sumA; s_sum[1][wave] = sumB; s_sum[2][wave] = sumC;
    }
    __syncthreads();
    if (tid == 0) {
        float A = 0.f, Bs = 0.f, C = 0.f;
        #pragma unroll
        for (int w = 0; w < 4; ++w) {
            A += s_sum[0][w]; Bs += s_sum[1][w]; C += s_sum[2][w];
        }
        partials[blockIdx.x] = make_float4(A, Bs, C, 0.0f);
    }
}

__global__ void __launch_bounds__(256)
dmloss_final(const float4* __restrict__ partials, float* __restrict__ out)
{
    const int tid = threadIdx.x;
    float A = 0.0f, Bs = 0.0f, C = 0.0f;
    #pragma unroll
    for (int i = tid; i < 2 * BB; i += 256) {
        float4 p = partials[i];
        A += p.x; Bs += p.y; C += p.z;
    }
    #pragma unroll
    for (int off = 32; off > 0; off >>= 1) {
        A  += __shfl_down(A, off);
        Bs += __shfl_down(Bs, off);
        C  += __shfl_down(C, off);
    }
    __shared__ float sA[4], sB[4], sC[4];
    const int wave = tid >> 6, lane = tid & 63;
    if (lane == 0) { sA[wave] = A; sB[wave] = Bs; sC[wave] = C; }
    __syncthreads();
    if (tid == 0) {
        float a  = sA[0] + sA[1] + sA[2] + sA[3];
        float bs = sB[0] + sB[1] + sB[2] + sB[3];
        float c  = sC[0] + sC[1] + sC[2] + sC[3];
        float loss_pred2gt = a / ((float)BB * (float)NN * 2.0f);
        float loss_set2set = bs / (2.0f * c + 1.0f) + loss_pred2gt;
        out[0] = 0.5f * loss_set2set;
    }
}

extern "C" void kernel_launch(void* const* d_in, const int* in_sizes, int n_in,
                              void* d_out, int out_size, void* d_ws, size_t ws_size,
                              hipStream_t stream)
{
    const float* ini   = (const float*)d_in[0];
    const float* pred  = (const float*)d_in[1];
    const float* gt    = (const float*)d_in[2];
    const float* kmask = (const float*)d_in[3];
    float4* partials = (float4*)d_ws;   // 2048 * 16 B = 32 KiB

    dmloss_main<<<dim3(2 * BB), dim3(256), 0, stream>>>(ini, pred, gt, kmask, partials);
    dmloss_final<<<dim3(1), dim3(256), 0, stream>>>(partials, (float*)d_out);
}